// Round 3
// baseline (185918.433 us; speedup 1.0000x reference)
//
#include <hip/hip_runtime.h>
#include <stdint.h>

// RBNN persistent kernel, R3: bit-exact R1 summation chains (ascending-k
// single-accumulator fmaf per neuron, bias last) — NO split-K (R2's split-K
// tree reduce flipped borderline spikes -> chaos). ILP from C=2 neurons/wave.
// Acts & pre in k-packed [k/4][b][4] float layout: one float4 load = 4 k.
// Weights wave-uniform -> scalar loads. 256 blocks x 256 thr, 2 gbar/step.
// Phase C (post/out over all t) verbatim from R1 (bit-matched, absmax 0.0).

#define TT 1024
#define BB 64
#define NIc 512
#define NPREc 2048
#define NADc 1024
#define NPOSTc 2048
#define NOUTc 512
#define KXc 1536
#define NBLK 256

typedef unsigned long long u64;

__global__ void k_bar_init(unsigned* __restrict__ bar) {
  if (threadIdx.x < 64) bar[threadIdx.x] = 0u;
}

// arrive/spin barrier: cnt at bar[0], gen at bar[32]; gen is monotone.
__device__ __forceinline__ void gbar(unsigned* cnt, unsigned* gen, unsigned target) {
  __syncthreads();
  if (threadIdx.x == 0) {
    __threadfence();
    unsigned prev = __hip_atomic_fetch_add(cnt, 1u, __ATOMIC_ACQ_REL,
                                           __HIP_MEMORY_SCOPE_AGENT);
    if (prev == (unsigned)NBLK * target - 1u) {
      __hip_atomic_store(gen, target, __ATOMIC_RELEASE, __HIP_MEMORY_SCOPE_AGENT);
    } else {
      while (__hip_atomic_load(gen, __ATOMIC_ACQUIRE, __HIP_MEMORY_SCOPE_AGENT) < target)
        __builtin_amdgcn_s_sleep(1);
    }
    __threadfence();
  }
  __syncthreads();
}

// act/pre packed layout: element (k,b) at [(k>>2)*256 + b*4 + (k&3)]
__global__ __launch_bounds__(256, 4) void rbnn_seq(
    const float* __restrict__ inp, const float* __restrict__ W_pre,
    const float* __restrict__ b_pre, const float* __restrict__ W_ad,
    const float* __restrict__ b_ad, float* __restrict__ preP,
    float* __restrict__ actA, float* __restrict__ actB,
    u64* __restrict__ spk_bits, unsigned* __restrict__ bar) {
  unsigned* cnt = bar;
  unsigned* gen = bar + 32;
  const int lane = threadIdx.x & 63;
  const int w = __builtin_amdgcn_readfirstlane((int)(threadIdx.x >> 6));
  const int blk = blockIdx.x;
  unsigned tgt = 1;

  // ---- prologue: actA = pack([x_0^T ; spikes0^T]); spk_bits[0] ----
  if (w == 0) {
    int r0 = blk * 2;
    float2 v;
    v.x = inp[(size_t)lane * NIc + r0];
    v.y = inp[(size_t)lane * NIc + r0 + 1];
    *(float2*)(actA + (r0 >> 2) * 256 + lane * 4 + (r0 & 3)) = v;
  } else if (w == 1) {
    float one = (blk >= 128) ? 1.f : 0.f;
    float4 v; v.x = one; v.y = one; v.z = one; v.w = one;
    *(float4*)(actA + (128 + blk) * 256 + lane * 4) = v;
    if (lane < 4) spk_bits[blk * 4 + lane] = (blk >= 128) ? ~0ull : 0ull;
  }
  gbar(cnt, gen, tgt); ++tgt;

  for (int t = 0; t < TT; ++t) {
    const float* cur = (t & 1) ? actB : actA;
    float* nxt = (t & 1) ? actA : actB;

    // ---- stage1: pre = spike(act @ W_pre.T + b_pre); 4 waves x C=2 ----
    {
      const int j0 = blk * 8 + w * 2;
      const float* wp0 = W_pre + (size_t)j0 * KXc;
      const float* wp1 = wp0 + KXc;
      const float* ap = cur + lane * 4;
      float a0 = 0.f, a1 = 0.f;
#pragma unroll 4
      for (int kk = 0; kk < 384; ++kk) {
        float4 x = *(const float4*)(ap + kk * 256);
        float4 p = *(const float4*)(wp0 + kk * 4);
        float4 q = *(const float4*)(wp1 + kk * 4);
        a0 = fmaf(x.x, p.x, a0); a0 = fmaf(x.y, p.y, a0);
        a0 = fmaf(x.z, p.z, a0); a0 = fmaf(x.w, p.w, a0);
        a1 = fmaf(x.x, q.x, a1); a1 = fmaf(x.y, q.y, a1);
        a1 = fmaf(x.z, q.z, a1); a1 = fmaf(x.w, q.w, a1);
      }
      float s0 = a0 + b_pre[j0];
      float s1 = a1 + b_pre[j0 + 1];
      float2 pv;
      pv.x = (s0 > 0.f) ? 1.f : 0.f;
      pv.y = (s1 > 0.f) ? 1.f : 0.f;
      *(float2*)(preP + (j0 >> 2) * 256 + lane * 4 + (j0 & 3)) = pv;
    }
    gbar(cnt, gen, tgt); ++tgt;

    // ---- stage2: ad = pre @ W_ad.T + b_ad; spk' = spike(ad + 0.5*spk) ----
    if (w < 2) {
      const int i0 = blk * 4 + w * 2;
      const float* wa0 = W_ad + (size_t)i0 * NPREc;
      const float* wa1 = wa0 + NPREc;
      const float* pp = preP + lane * 4;
      float a0 = 0.f, a1 = 0.f;
#pragma unroll 4
      for (int jj = 0; jj < 512; ++jj) {
        float4 x = *(const float4*)(pp + jj * 256);
        float4 p = *(const float4*)(wa0 + jj * 4);
        float4 q = *(const float4*)(wa1 + jj * 4);
        a0 = fmaf(x.x, p.x, a0); a0 = fmaf(x.y, p.y, a0);
        a0 = fmaf(x.z, p.z, a0); a0 = fmaf(x.w, p.w, a0);
        a1 = fmaf(x.x, q.x, a1); a1 = fmaf(x.y, q.y, a1);
        a1 = fmaf(x.z, q.z, a1); a1 = fmaf(x.w, q.w, a1);
      }
      const int r0 = 512 + i0;
      const int pbase = (r0 >> 2) * 256 + lane * 4 + (r0 & 3);
      float os0 = cur[pbase];
      float os1 = cur[pbase + 1];
      float ad0 = a0 + b_ad[i0];
      float ad1 = a1 + b_ad[i0 + 1];
      float v0 = ad0 + 0.5f * os0;
      float v1 = ad1 + 0.5f * os1;
      int nb0 = (v0 > 0.f) ? 1 : 0;
      int nb1 = (v1 > 0.f) ? 1 : 0;
      float2 nv; nv.x = (float)nb0; nv.y = (float)nb1;
      *(float2*)(nxt + pbase) = nv;
      u64 m0 = __ballot(nb0);
      u64 m1 = __ballot(nb1);
      if (lane == 0) {
        spk_bits[(size_t)(t + 1) * NADc + i0] = m0;
        spk_bits[(size_t)(t + 1) * NADc + i0 + 1] = m1;
      }
    } else if (w == 2 && t + 1 < TT) {
      int r0 = blk * 2;
      const float* xr = inp + ((size_t)(t + 1) * BB + lane) * NIc;
      float2 v; v.x = xr[r0]; v.y = xr[r0 + 1];
      *(float2*)(nxt + (r0 >> 2) * 256 + lane * 4 + (r0 & 3)) = v;
    }
    gbar(cnt, gen, tgt); ++tgt;
  }
}

// ---------- phase C1: post bits for all t (verbatim R1) ----------
__global__ __launch_bounds__(256) void k_post(
    const float* __restrict__ inp, const float* __restrict__ W_post,
    const float* __restrict__ b_post, const u64* __restrict__ spk_bits,
    u64* __restrict__ post_bits) {
  const int t = blockIdx.x;
  const int lane = threadIdx.x & 63;
  const int wave = threadIdx.x >> 6;
  int j0 = (blockIdx.y * 4 + wave) * 16;
  j0 = __builtin_amdgcn_readfirstlane(j0);
  const int b = lane;
  const float* xrow = inp + ((size_t)t * BB + b) * NIc;
  const u64* sbits = spk_bits + (size_t)(t + 1) * NADc;
  const float* wbase = W_post + (size_t)j0 * KXc;
  float acc[16];
#pragma unroll
  for (int q = 0; q < 16; ++q) acc[q] = 0.f;
  for (int i = 0; i < NIc; i += 4) {
    float4 x = *(const float4*)(xrow + i);
#pragma unroll
    for (int q = 0; q < 16; ++q) {
      float4 w = *(const float4*)(wbase + (size_t)q * KXc + i);
      acc[q] = fmaf(x.x, w.x, acc[q]); acc[q] = fmaf(x.y, w.y, acc[q]);
      acc[q] = fmaf(x.z, w.z, acc[q]); acc[q] = fmaf(x.w, w.w, acc[q]);
    }
  }
  for (int k = 0; k < NADc; k += 4) {
    float xs0 = (float)((unsigned)(sbits[k + 0] >> b) & 1u);
    float xs1 = (float)((unsigned)(sbits[k + 1] >> b) & 1u);
    float xs2 = (float)((unsigned)(sbits[k + 2] >> b) & 1u);
    float xs3 = (float)((unsigned)(sbits[k + 3] >> b) & 1u);
#pragma unroll
    for (int q = 0; q < 16; ++q) {
      float4 w = *(const float4*)(wbase + (size_t)q * KXc + NIc + k);
      acc[q] = fmaf(xs0, w.x, acc[q]); acc[q] = fmaf(xs1, w.y, acc[q]);
      acc[q] = fmaf(xs2, w.z, acc[q]); acc[q] = fmaf(xs3, w.w, acc[q]);
    }
  }
#pragma unroll
  for (int q = 0; q < 16; ++q) {
    float s = acc[q] + b_post[j0 + q];
    u64 m = __ballot(s > 0.f);
    if (lane == 0) post_bits[(size_t)t * NPOSTc + j0 + q] = m;
  }
}

// ---------- phase C2: o = post @ W_out.T + b_out (verbatim R1) ----------
__global__ __launch_bounds__(256) void k_out(
    const float* __restrict__ W_out, const float* __restrict__ b_out,
    const u64* __restrict__ post_bits, float* __restrict__ out) {
  const int t = blockIdx.x;
  const int lane = threadIdx.x & 63;
  const int wave = threadIdx.x >> 6;
  int n0 = (blockIdx.y * 4 + wave) * 16;
  n0 = __builtin_amdgcn_readfirstlane(n0);
  const int b = lane;
  const u64* pb = post_bits + (size_t)t * NPOSTc;
  const float* wbase = W_out + (size_t)n0 * NPOSTc;
  float acc[16];
#pragma unroll
  for (int q = 0; q < 16; ++q) acc[q] = 0.f;
  for (int j = 0; j < NPOSTc; j += 4) {
    float xs0 = (float)((unsigned)(pb[j + 0] >> b) & 1u);
    float xs1 = (float)((unsigned)(pb[j + 1] >> b) & 1u);
    float xs2 = (float)((unsigned)(pb[j + 2] >> b) & 1u);
    float xs3 = (float)((unsigned)(pb[j + 3] >> b) & 1u);
#pragma unroll
    for (int q = 0; q < 16; ++q) {
      float4 w = *(const float4*)(wbase + (size_t)q * NPOSTc + j);
      acc[q] = fmaf(xs0, w.x, acc[q]); acc[q] = fmaf(xs1, w.y, acc[q]);
      acc[q] = fmaf(xs2, w.z, acc[q]); acc[q] = fmaf(xs3, w.w, acc[q]);
    }
  }
  float* orow = out + ((size_t)t * BB + b) * NOUTc;
#pragma unroll
  for (int q = 0; q < 16; ++q) orow[n0 + q] = acc[q] + b_out[n0 + q];
}

// ---------- final_spikes -> d_out tail ----------
__global__ __launch_bounds__(256) void k_final(const u64* __restrict__ spk_last,
                                               float* __restrict__ out_tail) {
  int tid = blockIdx.x * 256 + threadIdx.x;  // 65536
  int b = tid >> 10, i = tid & 1023;
  out_tail[tid] = (float)((unsigned)(spk_last[i] >> b) & 1u);
}

extern "C" void kernel_launch(void* const* d_in, const int* in_sizes, int n_in,
                              void* d_out, int out_size, void* d_ws, size_t ws_size,
                              hipStream_t stream) {
  const float* inp    = (const float*)d_in[0];
  const float* W_pre  = (const float*)d_in[1];
  const float* b_pre  = (const float*)d_in[2];
  const float* W_ad   = (const float*)d_in[3];
  const float* b_ad   = (const float*)d_in[4];
  const float* W_post = (const float*)d_in[5];
  const float* b_post = (const float*)d_in[6];
  const float* W_out  = (const float*)d_in[7];
  const float* b_out  = (const float*)d_in[8];
  float* out = (float*)d_out;

  char* ws = (char*)d_ws;
  u64* spk_bits  = (u64*)ws;                     // [1025][1024] u64 = 8,396,800 B
  u64* post_bits = (u64*)(ws + 8396800);         // [1024][2048] u64 = 16,777,216 B
  float* preP    = (float*)(ws + 25174016);      // [512][64][4] f32 = 524,288 B
  float* actA    = (float*)(ws + 25698304);      // [384][64][4] f32 = 393,216 B
  float* actB    = (float*)(ws + 26091520);      // [384][64][4] f32 = 393,216 B
  unsigned* bar  = (unsigned*)(ws + 26484736);   // 256 B

  k_bar_init<<<1, 64, 0, stream>>>(bar);
  rbnn_seq<<<NBLK, 256, 0, stream>>>(inp, W_pre, b_pre, W_ad, b_ad,
                                     preP, actA, actB, spk_bits, bar);
  k_post<<<dim3(TT, 32), 256, 0, stream>>>(inp, W_post, b_post, spk_bits, post_bits);
  k_out<<<dim3(TT, 8), 256, 0, stream>>>(W_out, b_out, post_bits, out);
  k_final<<<256, 256, 0, stream>>>(spk_bits + (size_t)TT * NADc,
                                   out + (size_t)TT * BB * NOUTc);
}